// Round 1
// baseline (95.952 us; speedup 1.0000x reference)
//
#include <hip/hip_runtime.h>
#include <math.h>

// ---------------------------------------------------------------------------
// QuantumClassifier_v2 on MI355X — SINGLE fused kernel (no workspace).
//  128 blocks (1 per batch row) x 512 threads.
//  Phase A: wave0 lanes 0-39 build the 4 interferometers (MZI T-blocks +
//           register column sweep, warp-synchronous); wave2 does the GEMV
//           h=(x@Wd+bd)/pi with float4 loads + butterfly reduce -> v=e^{ih}.
//  U1 = WR1 diag(v) WL1 in LDS.
//  e1 (252 no-bunching probs):  product-of-linear-forms DP over subset levels
//           10 -> 45 -> 120 -> 210 -> 252   (coefficient c_S = perm(U1_S)).
//  phi2 fold -> UF = WRF diag(v) WLF in LDS.
//  bunched probs: same DP over multiset levels 10 -> 55 -> 220 -> 715 -> 2002,
//           prob_s = |c_s|^2 * prod(s_m!)  (perm = c_s * prod s_m!).
//  Epilogue: fused W_out GEMV in registers, block reduce, out = bias + sum.
// Combinadic ranking: lex rank(c;N,n) = C(N,n)-1 - sum_i C(N-1-c_i, n-i);
// parent ranks via prefix/suffix binomial sums, LUT C(a,b) a<=13,b<=5 in LDS.
// ---------------------------------------------------------------------------

#define PI_F 3.14159265358979323846f
#define BLK 512

__device__ __forceinline__ float2 cmul(float2 a, float2 b) {
  return make_float2(fmaf(a.x, b.x, -a.y * b.y), fmaf(a.x, b.y, a.y * b.x));
}
__device__ __forceinline__ float2 cadd(float2 a, float2 b) {
  return make_float2(a.x + b.x, a.y + b.y);
}
__device__ __forceinline__ float2 cscale(float2 a, float s) {
  return make_float2(a.x * s, a.y * s);
}
__device__ __forceinline__ float2 imul(float2 a) {  // i*a
  return make_float2(-a.y, a.x);
}

// Register-only lexicographic unranking of K-combinations (strictly
// increasing combinadic c[0..K-1] from {0..m0}); exact fp32 binomial walk.
template <int K>
__device__ __forceinline__ void unrankT(int rank, float cnt0, float m0,
                                        int c[5]) {
  float r = (float)rank;
  float cnt = cnt0, m = m0, j = (float)(K - 1);
  int x = 0;
#pragma unroll
  for (int i = 0; i < K; i++) {
    while (r >= cnt) {            // skip value x
      r -= cnt;
      cnt = cnt * (m - j) / m;    // C(m-1, j)
      m -= 1.f;
      x++;
    }
    c[i] = x;                     // take value x
    cnt = cnt * j / m;            // C(m-1, j-1)
    m -= 1.f;
    j -= 1.f;
    x++;
  }
}

// One DP gather: coefficient at level K from level K-1 parents.
//  MULTI=true : multisets of 10 modes, c_i = mode_i + i over {0..8+K}
//  MULTI=false: subsets  of 10 modes, c_i = mode_i     over {0..9}
// new_c[s] = sum_{distinct mode mu in s} prev[rank(s - e_mu)] * U[mu, 2(K-1)]
template <int K, bool MULTI>
__device__ __forceinline__ float2 dp_gather(const int c[5],
                                            const float2* __restrict__ prev,
                                            const float2* __restrict__ Ublk,
                                            const int* __restrict__ BL) {
  const int col = 2 * (K - 1);
  const int base = BL[(MULTI ? (8 + K) : 10) * 6 + (K - 1)] - 1;  // C(N',K-1)-1
  int sufa[6];
  sufa[K - 1] = 0;
#pragma unroll
  for (int j = K - 1; j >= 1; j--)
    sufa[j - 1] = sufa[j] + BL[((MULTI ? (8 + K) : 9) - c[j]) * 6 + (K - j)];
  float2 acc = make_float2(0.f, 0.f);
  int pa = 0;
#pragma unroll
  for (int p = 0; p < K; p++) {
    const int mp = MULTI ? (c[p] - p) : c[p];
    bool take = true;
    if (MULTI && p > 0) take = ((c[p] - p) != (c[p - 1] - (p - 1)));
    if (take) {
      const int R = base - pa - sufa[p];
      acc = cadd(acc, cmul(prev[R], Ublk[mp * 10 + col]));
    }
    if (p < K - 1)
      pa += BL[((MULTI ? (7 + K) : 9) - c[p]) * 6 + (K - 1 - p)];
  }
  return acc;
}

template <int K, bool MULTI>
__device__ __forceinline__ void dp_level(int tid, int size, float cnt0,
                                         float m0,
                                         const float2* __restrict__ prev,
                                         float2* __restrict__ cur,
                                         const float2* __restrict__ Ublk,
                                         const int* __restrict__ BL) {
  for (int r = tid; r < size; r += BLK) {
    int c[5];
    unrankT<K>(r, cnt0, m0, c);
    cur[r] = dp_gather<K, MULTI>(c, prev, Ublk, BL);
  }
}

__global__ __launch_bounds__(BLK) void k_fused(
    const float* __restrict__ x, const float* __restrict__ Wd,
    const float* __restrict__ bd, const float* __restrict__ ph_l1,
    const float* __restrict__ ph_r1, const float* __restrict__ ph_lf,
    const float* __restrict__ ph_rf, const float* __restrict__ bout,
    const float* __restrict__ Wout, float* __restrict__ out) {
  const int b = blockIdx.x, tid = threadIdx.x;

  __shared__ float2 T[4][45][4];   // MZI 2x2 blocks
  __shared__ float2 Ui[4][100];    // 0=WL1, 1=WR1, 2=WLF, 3=WRF
  __shared__ float2 Ub[100];       // U1, then UF
  __shared__ float2 dpA[220];      // DP ping  (max 220)
  __shared__ float2 dpB[715];      // DP pong  (max 715)
  __shared__ float  e1s[252];
  __shared__ float2 v[10];
  __shared__ float  red[BLK / 64][10];
  __shared__ int    BL[14 * 6];    // C(a,b), a 0..13, b 0..5

  // ---- binomial LUT (exact integer Pascal row per thread) ----
  if (tid < 14) {
    const int a = tid;
    int val = 1;
    BL[a * 6 + 0] = 1;
#pragma unroll
    for (int bb = 1; bb < 6; bb++) {
      val = (a >= bb) ? val * (a - bb + 1) / bb : 0;
      BL[a * 6 + bb] = val;
    }
  }

  if (tid < 64) {
    // ---- wave 0, lanes 0-39: T-blocks + register column sweep,
    //      warp-synchronous (same wave writes then reads T) ----
    if (tid < 40) {
      const int which = tid / 10, n = tid % 10;
      const float* ph = (which == 0) ? ph_l1
                      : (which == 1) ? ph_r1
                      : (which == 2) ? ph_lf : ph_rf;
#pragma unroll
      for (int t5 = 0; t5 < 5; t5++) {
        const int m = n + 10 * t5;
        if (m < 45) {
          float t1 = ph[m * 2 + 0], t2 = ph[m * 2 + 1];
          float s1, c1, s2, c2;
          __sincosf(t1, &s1, &c1);
          __sincosf(t2, &s2, &c2);
          float2 e2  = make_float2(c2, s2);
          float2 e1m = make_float2(c1 - 1.f, s1);
          float2 e1p = make_float2(c1 + 1.f, s1);
          T[which][m][0] = cscale(cmul(e2, e1m), 0.5f);
          T[which][m][1] = cscale(cmul(e2, imul(e1p)), 0.5f);
          T[which][m][2] = cscale(imul(e1p), 0.5f);
          T[which][m][3] = make_float2(0.5f * (1.f - c1), -0.5f * s1);
        }
      }
      // column sweep: this thread owns column n of interferometer `which`
      float2 u[10];
#pragma unroll
      for (int m = 0; m < 10; m++)
        u[m] = make_float2(m == n ? 1.f : 0.f, 0.f);
      int kb = 0;
#pragma unroll
      for (int layer = 0; layer < 10; layer++) {
        const int start = layer & 1;
        const int npairs = 5 - start;
#pragma unroll
        for (int pi = 0; pi < 5; pi++) {
          if (pi < npairs) {
            const int p = start + 2 * pi;
            const int k = kb + pi;
            float2 u0 = u[p], u1 = u[p + 1];
            u[p]     = cadd(cmul(T[which][k][0], u0), cmul(T[which][k][1], u1));
            u[p + 1] = cadd(cmul(T[which][k][2], u0), cmul(T[which][k][3], u1));
          }
        }
        kb += npairs;
      }
#pragma unroll
      for (int m = 0; m < 10; m++) Ui[which][m * 10 + n] = u[m];
    }
  } else if (tid >= 128 && tid < 192) {
    // ---- wave 2: whole GEMV + in-wave reduce + v = e^{ih} ----
    const int lane = tid - 128;
    float acc[10];
#pragma unroll
    for (int c = 0; c < 10; c++) acc[c] = 0.f;
    const float4* x4 = (const float4*)(x + b * 784);  // 196 float4
#pragma unroll
    for (int it = 0; it < 4; it++) {
      const int q = lane + it * 64;
      if (q < 196) {
        float4 xv = x4[q];
        const float4* w4 = (const float4*)(Wd + 40 * q);
        float W[40];
#pragma unroll
        for (int j = 0; j < 10; j++) {
          float4 wv = w4[j];
          W[4 * j + 0] = wv.x; W[4 * j + 1] = wv.y;
          W[4 * j + 2] = wv.z; W[4 * j + 3] = wv.w;
        }
        const float xe[4] = {xv.x, xv.y, xv.z, xv.w};
#pragma unroll
        for (int s = 0; s < 40; s++)
          acc[s % 10] = fmaf(xe[s / 10], W[s], acc[s % 10]);
      }
    }
#pragma unroll
    for (int d = 32; d > 0; d >>= 1)
#pragma unroll
      for (int c = 0; c < 10; c++) acc[c] += __shfl_xor(acc[c], d);
    if (lane < 10) {
      float s = (acc[lane] + bd[lane]) * (1.0f / PI_F);
      float sn, cs;
      __sincosf(s, &sn, &cs);
      v[lane] = make_float2(cs, sn);
    }
  }
  __syncthreads();  // (1) Ui, v, BL ready

  // ---- U1 = WR1 diag(v) WL1 (diag fused) ----
  if (tid < 100) {
    const int m = tid / 10, n = tid % 10;
    float2 acc = make_float2(0.f, 0.f);
#pragma unroll
    for (int k = 0; k < 10; k++)
      acc = cadd(acc, cmul(cmul(Ui[1][m * 10 + k], v[k]), Ui[0][k * 10 + n]));
    Ub[tid] = acc;
  }
  __syncthreads();  // (2) U1 ready

  // ---- e1: subset DP  10 -> 45 -> 120 -> 210 -> 252 ----
  if (tid < 10) dpA[tid] = Ub[tid * 10];  // level 1: B1[m][0]
  __syncthreads();  // (3)
  dp_level<2, false>(tid, 45, 9.f, 9.f, dpA, dpB, Ub, BL);
  __syncthreads();  // (4)
  dp_level<3, false>(tid, 120, 36.f, 9.f, dpB, dpA, Ub, BL);
  __syncthreads();  // (5)
  dp_level<4, false>(tid, 210, 84.f, 9.f, dpA, dpB, Ub, BL);
  __syncthreads();  // (6)
  for (int r = tid; r < 252; r += BLK) {  // level 5 -> |c_S|^2 (norm = 1)
    int c[5];
    unrankT<5>(r, 126.f, 9.f, c);
    float2 a = dp_gather<5, false>(c, dpB, Ub, BL);
    e1s[r] = a.x * a.x + a.y * a.y;
  }
  __syncthreads();  // (7) e1 ready

  // ---- phi2 fold + v = e^{i phi2} ----
  if (tid < 10) {
    float s = 0.f;
    for (int idx = tid; idx < 252; idx += 10) s += e1s[idx];
    float sn, cs;
    __sincosf(s, &sn, &cs);
    v[tid] = make_float2(cs, sn);
  }
  __syncthreads();  // (8) v ready

  // ---- UF = WRF diag(v) WLF ----
  if (tid < 100) {
    const int m = tid / 10, n = tid % 10;
    float2 acc = make_float2(0.f, 0.f);
#pragma unroll
    for (int k = 0; k < 10; k++)
      acc = cadd(acc, cmul(cmul(Ui[3][m * 10 + k], v[k]), Ui[2][k * 10 + n]));
    Ub[tid] = acc;
  }
  __syncthreads();  // (9) UF ready

  // ---- bunched: multiset DP  10 -> 55 -> 220 -> 715 -> 2002 ----
  if (tid < 10) dpA[tid] = Ub[tid * 10];  // level 1: B[m][0]
  __syncthreads();  // (10)
  dp_level<2, true>(tid, 55, 10.f, 10.f, dpA, dpB, Ub, BL);
  __syncthreads();  // (11)
  dp_level<3, true>(tid, 220, 55.f, 11.f, dpB, dpA, Ub, BL);
  __syncthreads();  // (12)
  dp_level<4, true>(tid, 715, 220.f, 12.f, dpA, dpB, Ub, BL);
  __syncthreads();  // (13)

  // ---- level 5 fused with W_out epilogue ----
  float accO[10];
#pragma unroll
  for (int c = 0; c < 10; c++) accO[c] = 0.f;
  for (int r = tid; r < 2002; r += BLK) {
    int c5[5];
    unrankT<5>(r, 715.f, 13.f, c5);
    float2 a = dp_gather<5, true>(c5, dpB, Ub, BL);
    // prob = |c_s|^2 * prod(s_m!)  via run-length product over sorted modes
    float norm = 1.f, cnt = 1.f;
#pragma unroll
    for (int i = 1; i < 5; i++) {
      cnt = ((c5[i] - i) == (c5[i - 1] - (i - 1))) ? cnt + 1.f : 1.f;
      norm *= cnt;
    }
    const float pv = (a.x * a.x + a.y * a.y) * norm;
    const float2* w2 = (const float2*)Wout + r * 5;
#pragma unroll
    for (int j = 0; j < 5; j++) {
      float2 w = w2[j];
      accO[2 * j + 0] = fmaf(pv, w.x, accO[2 * j + 0]);
      accO[2 * j + 1] = fmaf(pv, w.y, accO[2 * j + 1]);
    }
  }

  const int lane = tid & 63, wv = tid >> 6;
#pragma unroll
  for (int c = 0; c < 10; c++) {
    float rsum = accO[c];
#pragma unroll
    for (int d = 32; d > 0; d >>= 1) rsum += __shfl_down(rsum, d);
    if (lane == 0) red[wv][c] = rsum;
  }
  __syncthreads();  // (14)
  if (tid < 10) {
    float s = bout[tid];
#pragma unroll
    for (int w = 0; w < BLK / 64; w++) s += red[w][tid];
    out[b * 10 + tid] = s;
  }
}

extern "C" void kernel_launch(void* const* d_in, const int* in_sizes, int n_in,
                              void* d_out, int out_size, void* d_ws,
                              size_t ws_size, hipStream_t stream) {
  const float* x    = (const float*)d_in[0];  // [128,784]
  const float* Wd   = (const float*)d_in[1];  // [784,10]
  const float* bd   = (const float*)d_in[2];  // [10]
  const float* pl1  = (const float*)d_in[3];  // [45,2]
  const float* pr1  = (const float*)d_in[4];  // [45,2]
  const float* plf  = (const float*)d_in[5];  // [45,2]
  const float* prf  = (const float*)d_in[6];  // [45,2]
  const float* Wout = (const float*)d_in[7];  // [2002,10]
  const float* bout = (const float*)d_in[8];  // [10]
  float* out = (float*)d_out;                 // [128,10]

  (void)d_ws; (void)ws_size;  // workspace unused — single fused kernel
  k_fused<<<128, BLK, 0, stream>>>(x, Wd, bd, pl1, pr1, plf, prf, bout, Wout,
                                   out);
}

// Round 2
// 86.167 us; speedup vs baseline: 1.1136x; 1.1136x over previous
//
#include <hip/hip_runtime.h>
#include <math.h>

// ---------------------------------------------------------------------------
// QuantumClassifier_v2 on MI355X, two kernels (R4 structure, prefix
// wave-specialized):
//  k_prefix (128 blocks, 1/row):
//    wave0 lanes 0-39: MZI T-blocks + register column sweep for the 4
//      interferometers, warp-synchronous (DS ops of a wave are in-order —
//      no barrier between T write and read).
//    wave2: whole GEMV h=(x[b]@Wd+bd)/pi with float4 loads, in-wave butterfly
//      reduce, writes v=e^{ih}. Overlaps the interferometer build.
//    then: U1 (diag fused) -> e1 (252 perms) -> phi2 -> UF -> ws. 4 barriers.
//  k_perms (1024 blocks, 8/row): one bunched permanent per thread, fused
//    with W_out; block-reduce + atomicAdd into out (seeded with b_out).
// Unranking = register-only binomial walk (exact fp32; values < 2^14).
//
// R1 post-mortem (kept as a journal note): a product-of-linear-forms DP
// (10->55->220->715->2002) replaced the 2002 Glynn permanents and REGRESSED
// ~10 us: the DP is a barrier-separated LDS-latency chain dominated by
// fp32-divide unranking, while perm5 is pure-FMA at the fp32 vector
// roofline (~218 MFLOP total = 1.39 us ideal). Do not retry FLOP-count
// reductions that trade dense FMA for dependent LDS gathers.
// ---------------------------------------------------------------------------

#define PI_F 3.14159265358979323846f

__device__ __forceinline__ float2 cmul(float2 a, float2 b) {
  return make_float2(fmaf(a.x, b.x, -a.y * b.y), fmaf(a.x, b.y, a.y * b.x));
}
__device__ __forceinline__ float2 cadd(float2 a, float2 b) {
  return make_float2(a.x + b.x, a.y + b.y);
}
__device__ __forceinline__ float2 cscale(float2 a, float s) {
  return make_float2(a.x * s, a.y * s);
}
__device__ __forceinline__ float2 imul(float2 a) {  // i*a
  return make_float2(-a.y, a.x);
}

// Register-only lexicographic unranking of 5-combinations of {0..N-1}.
__device__ __forceinline__ void unrank5f(int rank, float cnt0, float m0,
                                         int c[5]) {
  float r = (float)rank;
  float cnt = cnt0, m = m0, j = 4.f;
  int x = 0;
#pragma unroll
  for (int i = 0; i < 5; i++) {
    while (r >= cnt) {            // skip value x
      r -= cnt;
      cnt = cnt * (m - j) / m;    // C(m-1, j)
      m -= 1.f;
      x++;
    }
    c[i] = x;                     // take value x
    cnt = cnt * j / m;            // C(m-1, j-1)
    m -= 1.f;
    j -= 1.f;
    x++;
  }
}

__device__ __forceinline__ float2 prod5(const float2 rs[5]) {
  return cmul(cmul(cmul(rs[0], rs[1]), cmul(rs[2], rs[3])), rs[4]);
}

// Glynn permanent of 5x5 complex, Gray-code, fully unrolled (result = sum/16).
__device__ __forceinline__ float2 perm5(const float2 M[5][5]) {
  float2 rs[5];
#pragma unroll
  for (int j = 0; j < 5; j++) {
    rs[j] = M[0][j];
#pragma unroll
    for (int i = 1; i < 5; i++) rs[j] = cadd(rs[j], M[i][j]);
  }
  float2 acc = prod5(rs);
#pragma unroll
  for (int t = 1; t < 16; t++) {
    const int g = t ^ (t >> 1);
    const int bit = (t & 1) ? 0 : ((t & 2) ? 1 : ((t & 4) ? 2 : 3));  // ctz
    const int i = bit + 1;
    const float step = ((g >> bit) & 1) ? -2.0f : 2.0f;
#pragma unroll
    for (int j = 0; j < 5; j++) {
      rs[j].x = fmaf(step, M[i][j].x, rs[j].x);
      rs[j].y = fmaf(step, M[i][j].y, rs[j].y);
    }
    float2 p = prod5(rs);
    const float s = (__popc(g) & 1) ? -1.0f : 1.0f;
    acc.x = fmaf(s, p.x, acc.x);
    acc.y = fmaf(s, p.y, acc.y);
  }
  return make_float2(acc.x * (1.0f / 16.0f), acc.y * (1.0f / 16.0f));
}

// ---------------------------------------------------------------------------
// Kernel 1: everything through UF; one block per batch row.
// ---------------------------------------------------------------------------
__global__ __launch_bounds__(256) void k_prefix(
    const float* __restrict__ x, const float* __restrict__ Wd,
    const float* __restrict__ bd, const float* __restrict__ ph_l1,
    const float* __restrict__ ph_r1, const float* __restrict__ ph_lf,
    const float* __restrict__ ph_rf, const float* __restrict__ bout,
    float2* __restrict__ UFws, float* __restrict__ out) {
  const int b = blockIdx.x, tid = threadIdx.x;

  __shared__ float2 T[4][45][4];   // MZI 2x2 blocks
  __shared__ float2 Ui[4][100];    // 0=WL1, 1=WR1, 2=WLF, 3=WRF
  __shared__ float2 Ub[100];       // U1, then UF
  __shared__ float  e1s[252];
  __shared__ float2 v[10];

  if (tid < 64) {
    // ---- wave 0, lanes 0-39: T-blocks + register column sweep,
    //      warp-synchronous (same wave writes then reads T) ----
    if (tid < 40) {
      const int which = tid / 10, n = tid % 10;
      const float* ph = (which == 0) ? ph_l1
                      : (which == 1) ? ph_r1
                      : (which == 2) ? ph_lf : ph_rf;
      // lane (which,n) computes T for MZIs m = n, n+10, ..., <45
#pragma unroll
      for (int t5 = 0; t5 < 5; t5++) {
        const int m = n + 10 * t5;
        if (m < 45) {
          float t1 = ph[m * 2 + 0], t2 = ph[m * 2 + 1];
          float s1, c1, s2, c2;
          __sincosf(t1, &s1, &c1);
          __sincosf(t2, &s2, &c2);
          float2 e2  = make_float2(c2, s2);
          float2 e1m = make_float2(c1 - 1.f, s1);
          float2 e1p = make_float2(c1 + 1.f, s1);
          T[which][m][0] = cscale(cmul(e2, e1m), 0.5f);
          T[which][m][1] = cscale(cmul(e2, imul(e1p)), 0.5f);
          T[which][m][2] = cscale(imul(e1p), 0.5f);
          T[which][m][3] = make_float2(0.5f * (1.f - c1), -0.5f * s1);
        }
      }
      // column sweep: this thread owns column n of interferometer `which`
      float2 u[10];
#pragma unroll
      for (int m = 0; m < 10; m++)
        u[m] = make_float2(m == n ? 1.f : 0.f, 0.f);
      int kb = 0;
#pragma unroll
      for (int layer = 0; layer < 10; layer++) {
        const int start = layer & 1;
        const int npairs = 5 - start;
#pragma unroll
        for (int pi = 0; pi < 5; pi++) {
          if (pi < npairs) {
            const int p = start + 2 * pi;
            const int k = kb + pi;
            float2 u0 = u[p], u1 = u[p + 1];
            u[p]     = cadd(cmul(T[which][k][0], u0), cmul(T[which][k][1], u1));
            u[p + 1] = cadd(cmul(T[which][k][2], u0), cmul(T[which][k][3], u1));
          }
        }
        kb += npairs;
      }
#pragma unroll
      for (int m = 0; m < 10; m++) Ui[which][m * 10 + n] = u[m];
    }
  } else if (tid >= 128 && tid < 192) {
    // ---- wave 2: whole GEMV + in-wave reduce + v = e^{ih} ----
    const int lane = tid - 128;
    float acc[10];
#pragma unroll
    for (int c = 0; c < 10; c++) acc[c] = 0.f;
    const float4* x4 = (const float4*)(x + b * 784);  // 196 float4, 16B-aligned
#pragma unroll
    for (int it = 0; it < 4; it++) {
      const int q = lane + it * 64;
      if (q < 196) {
        float4 xv = x4[q];
        const float4* w4 = (const float4*)(Wd + 40 * q);  // 160B-aligned
        float W[40];
#pragma unroll
        for (int j = 0; j < 10; j++) {
          float4 wv = w4[j];
          W[4 * j + 0] = wv.x; W[4 * j + 1] = wv.y;
          W[4 * j + 2] = wv.z; W[4 * j + 3] = wv.w;
        }
        const float xe[4] = {xv.x, xv.y, xv.z, xv.w};
#pragma unroll
        for (int s = 0; s < 40; s++)
          acc[s % 10] = fmaf(xe[s / 10], W[s], acc[s % 10]);
      }
    }
    // 64-lane butterfly: every lane ends with all 10 totals
#pragma unroll
    for (int d = 32; d > 0; d >>= 1)
#pragma unroll
      for (int c = 0; c < 10; c++) acc[c] += __shfl_xor(acc[c], d);
    if (lane < 10) {
      float s = (acc[lane] + bd[lane]) * (1.0f / PI_F);
      float sn, cs;
      __sincosf(s, &sn, &cs);
      v[lane] = make_float2(cs, sn);
    }
  }
  __syncthreads();  // (1) Ui, v ready

  // ---- U1 = WR1 diag(v) WL1 (diag fused) ----
  if (tid < 100) {
    const int m = tid / 10, n = tid % 10;
    float2 acc = make_float2(0.f, 0.f);
#pragma unroll
    for (int k = 0; k < 10; k++)
      acc = cadd(acc, cmul(cmul(Ui[1][m * 10 + k], v[k]), Ui[0][k * 10 + n]));
    Ub[tid] = acc;
  }
  __syncthreads();  // (2) U1 ready

  // ---- e1: 252 no-bunching permanents ----
  if (tid < 252) {
    int c[5];
    unrank5f(tid, 126.f, 9.f, c);  // C(9,4)=126
    float2 M[5][5];
#pragma unroll
    for (int i = 0; i < 5; i++)
#pragma unroll
      for (int j = 0; j < 5; j++) M[i][j] = Ub[c[i] * 10 + 2 * j];
    float2 p = perm5(M);
    e1s[tid] = p.x * p.x + p.y * p.y;
  }
  __syncthreads();  // (3) e1 ready

  // ---- phi2 fold + v = e^{i phi2} ----
  if (tid < 10) {
    float s = 0.f;
    for (int idx = tid; idx < 252; idx += 10) s += e1s[idx];
    float sn, cs;
    __sincosf(s, &sn, &cs);
    v[tid] = make_float2(cs, sn);
  }
  __syncthreads();  // (4) v ready

  // ---- UF = WRF diag(v) WLF -> global ws ----
  if (tid < 100) {
    const int m = tid / 10, n = tid % 10;
    float2 acc = make_float2(0.f, 0.f);
#pragma unroll
    for (int k = 0; k < 10; k++)
      acc = cadd(acc, cmul(cmul(Ui[3][m * 10 + k], v[k]), Ui[2][k * 10 + n]));
    UFws[b * 100 + tid] = acc;
  }
  if (tid < 10) out[b * 10 + tid] = bout[tid];  // seed bias
}

// ---------------------------------------------------------------------------
// Kernel 2: 8 blocks per batch row; one bunched permanent per thread.
// ---------------------------------------------------------------------------
__global__ __launch_bounds__(256) void k_perms(const float2* __restrict__ UFws,
                                               const float* __restrict__ Wout,
                                               float* __restrict__ out) {
  const int b = blockIdx.x >> 3, chunk = blockIdx.x & 7;
  const int tid = threadIdx.x;
  const int k = chunk * 256 + tid;
  __shared__ float2 U[100];
  __shared__ float red[4][10];
  if (tid < 50)  // float4 staging: 2 complex per thread
    ((float4*)U)[tid] = ((const float4*)(UFws + b * 100))[tid];
  __syncthreads();

  float acc[10];
#pragma unroll
  for (int c = 0; c < 10; c++) acc[c] = 0.f;

  if (k < 2002) {
    int c5[5];
    unrank5f(k, 715.f, 13.f, c5);  // C(13,4)=715
    int modes[5];
#pragma unroll
    for (int i = 0; i < 5; i++) modes[i] = c5[i] - i;  // non-decreasing
    float2 M[5][5];
#pragma unroll
    for (int i = 0; i < 5; i++)
#pragma unroll
      for (int j = 0; j < 5; j++) M[i][j] = U[modes[i] * 10 + 2 * j];
    float2 p = perm5(M);
    // norm = prod of factorials of multiplicities via run-position product
    float norm = 1.f, cnt = 1.f;
#pragma unroll
    for (int i = 1; i < 5; i++) {
      cnt = (modes[i] == modes[i - 1]) ? cnt + 1.f : 1.f;
      norm *= cnt;
    }
    const float pv = (p.x * p.x + p.y * p.y) / norm;
    const float2* w2 = (const float2*)Wout + k * 5;
#pragma unroll
    for (int c = 0; c < 5; c++) {
      float2 w = w2[c];
      acc[2 * c + 0] = pv * w.x;
      acc[2 * c + 1] = pv * w.y;
    }
  }

  const int lane = tid & 63, wave = tid >> 6;
#pragma unroll
  for (int c = 0; c < 10; c++) {
    float r = acc[c];
#pragma unroll
    for (int d = 32; d > 0; d >>= 1) r += __shfl_down(r, d);
    if (lane == 0) red[wave][c] = r;
  }
  __syncthreads();
  if (tid < 10) {
    float s = red[0][tid] + red[1][tid] + red[2][tid] + red[3][tid];
    atomicAdd(&out[b * 10 + tid], s);
  }
}

extern "C" void kernel_launch(void* const* d_in, const int* in_sizes, int n_in,
                              void* d_out, int out_size, void* d_ws,
                              size_t ws_size, hipStream_t stream) {
  const float* x    = (const float*)d_in[0];  // [128,784]
  const float* Wd   = (const float*)d_in[1];  // [784,10]
  const float* bd   = (const float*)d_in[2];  // [10]
  const float* pl1  = (const float*)d_in[3];  // [45,2]
  const float* pr1  = (const float*)d_in[4];  // [45,2]
  const float* plf  = (const float*)d_in[5];  // [45,2]
  const float* prf  = (const float*)d_in[6];  // [45,2]
  const float* Wout = (const float*)d_in[7];  // [2002,10]
  const float* bout = (const float*)d_in[8];  // [10]
  float* out = (float*)d_out;                 // [128,10]

  float2* UFws = (float2*)d_ws;  // 128*100 complex64 = 100 KiB

  k_prefix<<<128, 256, 0, stream>>>(x, Wd, bd, pl1, pr1, plf, prf, bout, UFws,
                                    out);
  k_perms<<<1024, 256, 0, stream>>>(UFws, Wout, out);
}